// Round 5
// baseline (165.818 us; speedup 1.0000x reference)
//
#include <hip/hip_runtime.h>
#include <hip/hip_bf16.h>

#define N_NODES 100000
#define E_TOTAL 800000
#define E1      400000    // first min(4,k_max)*N edges -> scale-1 (subset of scale-2)
#define D       64
#define CAP     32        // max degree slots; P(deg>32 | Poisson(8)) ~ 2e-11/node

// ---- bucketed CSR build ----------------------------------------------------
#define NPB        128                            // nodes per bucket
#define NB         ((N_NODES + NPB - 1) / NPB)    // 782 buckets
#define BSTRIDE    (NPB * CAP)                    // 4096 u32: records alias entries span
#define BCAP       1536                           // mean 1024, sigma~32 -> 16 sigma margin
#define EPB        2048                           // edges per bucket-pass block
#define NBKT_BLKS  ((E_TOTAL + EPB - 1) / EPB)    // 391
#define PREP_TPB   512
#define EPT        (EPB / PREP_TPB)               // 4 edges/thread

typedef short s16x8 __attribute__((ext_vector_type(8)));   // 8 bf16 bit patterns
typedef float f32x4 __attribute__((ext_vector_type(4)));
typedef unsigned u32x4 __attribute__((ext_vector_type(4)));

// ws layout (u32 units):
//   cnt[N] | entries[N*CAP] | W1b[2048] | W2b[2048] | Wgb[4096] | bias[192] | cur[800]
// cnt[n] packs: true_deg (low 16) | placed_scale1_count (high 16)
// entries: per node CAP slots, scale-1 edges first, then scale-2-only, rest ZERO.
#define WS_CNT     0
#define WS_ENTRIES (N_NODES)                        // byte 400000, 16-B aligned
#define WS_W1B     (WS_ENTRIES + N_NODES * CAP)
#define WS_W2B     (WS_W1B + 2048)
#define WS_WGB     (WS_W2B + 2048)
#define WS_BIAS    (WS_WGB + 4096)                  // b1[64] | b2[64] | bg[64] fp32
#define WS_CUR     (WS_BIAS + 192)                  // NB bucket cursors (pad to 800)

// prep tail: weights/bias conversion (2048 + 24 threads, 512/block)
#define PREP_CONV_BLOCKS 5

__device__ __forceinline__ float ldv(const void* p, size_t idx, int fp32)
{
    return fp32 ? ((const float*)p)[idx]
                : __bfloat162float(((const __hip_bfloat16*)p)[idx]);
}

// block-local dtype detection.
__device__ __forceinline__ void detect2(const int* ei, const unsigned short* xu,
                                        int* s2, int& e64, int& fp32)
{
    if (threadIdx.x == 0) { s2[0] = 0; s2[1] = 0; }
    __syncthreads();
    if (threadIdx.x < 16 && ei[2 * threadIdx.x + 1] != 0) atomicOr(&s2[0], 1);
    { unsigned u = xu[threadIdx.x]; if (((u >> 7) & 0xFF) >= 0x90) atomicOr(&s2[1], 1); }
    __syncthreads();
    e64 = (s2[0] == 0); fp32 = s2[1];
}

// ---------------------------------------------------------------------------
// prep: 391 bucket blocks (512 thr, 2048 edges each) bin edges into coarse
// buckets via LDS-aggregated cursors; packed records alias the entries
// region. Trailing 5 blocks convert weights->bf16, biases->f32.
// No x conversion anywhere: fused gathers x directly (fp32 or bf16).
// ---------------------------------------------------------------------------
__global__ __launch_bounds__(512) void prep_kernel(
    const void* __restrict__ xv, const int* __restrict__ ei,
    const void* __restrict__ W1v, const void* __restrict__ b1v,
    const void* __restrict__ W2v, const void* __restrict__ b2v,
    const void* __restrict__ Wgv, const void* __restrict__ bgv,
    unsigned* __restrict__ ws)
{
    __shared__ int s2[2];
    __shared__ unsigned hist[NB];
    __shared__ unsigned bbase[NB];
    int e64, fp32;
    detect2(ei, (const unsigned short*)xv, s2, e64, fp32);

    if (blockIdx.x < NBKT_BLKS) {                 // ---- bucket pass ----
        for (int j = threadIdx.x; j < NB; j += PREP_TPB) hist[j] = 0;
        __syncthreads();

        const int e0 = blockIdx.x * EPB;
        int srcv[EPT], tgtv[EPT];
#pragma unroll
        for (int i = 0; i < EPT; ++i) {           // phase 1: all loads in flight
            const int e = e0 + i * PREP_TPB + threadIdx.x;
            srcv[i] = -1;
            if (e < E_TOTAL) {
                if (e64) {
                    srcv[i] = (int)((const uint2*)ei)[e].x;
                    tgtv[i] = (int)((const uint2*)ei)[E_TOTAL + e].x;
                } else {
                    srcv[i] = ei[e]; tgtv[i] = ei[E_TOTAL + e];
                }
            }
        }
        unsigned recv[EPT], br[EPT];
#pragma unroll
        for (int i = 0; i < EPT; ++i) {           // phase 2: LDS rank
            const int e = e0 + i * PREP_TPB + threadIdx.x;
            br[i] = 0xFFFFFFFFu;
            if (srcv[i] >= 0) {
                const unsigned b = (unsigned)srcv[i] >> 7;   // bucket (NPB=128)
                const unsigned r = atomicAdd(&hist[b], 1u);  // LDS rank (< 2048)
                recv[i] = (unsigned)tgtv[i]
                        | ((e < E1) ? 0x20000u : 0u)
                        | (((unsigned)srcv[i] & (NPB - 1)) << 18);
                br[i] = (b << 16) | r;
            }
        }
        __syncthreads();
        for (int j = threadIdx.x; j < NB; j += PREP_TPB) {
            const unsigned h = hist[j];
            bbase[j] = h ? atomicAdd(ws + WS_CUR + j, h) : 0u;
        }
        __syncthreads();
#pragma unroll
        for (int i = 0; i < EPT; ++i) {
            if (br[i] != 0xFFFFFFFFu) {
                const unsigned b = br[i] >> 16, r = br[i] & 0xFFFFu;
                const unsigned pos = bbase[b] + r;
                if (pos < BCAP)
                    ws[WS_ENTRIES + (size_t)b * BSTRIDE + pos] = recv[i];
            }
        }
        return;
    }

    // ---- weights / bias conversion ----
    const int gid = (blockIdx.x - NBKT_BLKS) * PREP_TPB + threadIdx.x;
    __hip_bfloat16* W1b = (__hip_bfloat16*)(ws + WS_W1B);
    __hip_bfloat16* W2b = (__hip_bfloat16*)(ws + WS_W2B);
    __hip_bfloat16* Wgb = (__hip_bfloat16*)(ws + WS_WGB);
    float* bias = (float*)(ws + WS_BIAS);

    if (gid < 2048) {                         // weights: 16384 elems, 8/thread
#pragma unroll
        for (int k = 0; k < 8; ++k) {
            const int i = gid * 8 + k;
            if (i < 4096)       W1b[i]        = __float2bfloat16(ldv(W1v, i, fp32));
            else if (i < 8192)  W2b[i - 4096] = __float2bfloat16(ldv(W2v, i - 4096, fp32));
            else                Wgb[i - 8192] = __float2bfloat16(ldv(Wgv, i - 8192, fp32));
        }
    } else if (gid < 2072) {                  // biases: 192 elems
        const int j = gid - 2048;
#pragma unroll
        for (int k = 0; k < 8; ++k) {
            const int i = j * 8 + k;
            if (i < 64)       bias[i] = ldv(b1v, i, fp32);
            else if (i < 128) bias[i] = ldv(b2v, i - 64, fp32);
            else              bias[i] = ldv(bgv, i - 128, fp32);
        }
    }
}

// ---------------------------------------------------------------------------
// csr_kernel: one block per bucket. Stages the bucket's records in LDS,
// counts per (node, class), then places scale-1 entries at [0, p1) and
// scale-2-only at [p1, deg) per node; unused slots are ZERO. Writes entries
// coalesced + packed cnt = true_deg | p1<<16. This ordering lets fused drop
// ballots/flag-bits: flag(j) = (j < p1).
// ---------------------------------------------------------------------------
__global__ __launch_bounds__(256) void csr_kernel(unsigned* __restrict__ ws)
{
    __shared__ unsigned rec_s[BCAP];                    // 6 KB
    __shared__ __align__(16) unsigned ent[NPB * CAP];   // 16 KB
    __shared__ unsigned n1c[NPB], ctc[NPB], a1[NPB], a2[NPB];

    const int b  = blockIdx.x;
    const int n0 = b * NPB;
    const int nn = min(NPB, N_NODES - n0);

    for (int j = threadIdx.x; j < NPB; j += 256) { n1c[j] = 0; ctc[j] = 0; }
    {
        const u32x4 z = {0u, 0u, 0u, 0u};
        for (int j = threadIdx.x; j < NPB * CAP / 4; j += 256) ((u32x4*)ent)[j] = z;
    }
    const unsigned C = min(ws[WS_CUR + b], (unsigned)BCAP);
    for (unsigned r = threadIdx.x; r < C; r += 256)
        rec_s[r] = ws[WS_ENTRIES + (size_t)b * BSTRIDE + r];
    __syncthreads();

    for (unsigned r = threadIdx.x; r < C; r += 256) {   // pass 1: counts
        const unsigned rec = rec_s[r];
        const unsigned sl  = rec >> 18;
        atomicAdd(&ctc[sl], 1u);
        if (rec & 0x20000u) atomicAdd(&n1c[sl], 1u);
    }
    __syncthreads();
    for (int j = threadIdx.x; j < NPB; j += 256) {
        a1[j] = 0u;
        a2[j] = min(n1c[j], (unsigned)CAP);             // scale-2-only start
    }
    __syncthreads();
    for (unsigned r = threadIdx.x; r < C; r += 256) {   // pass 2: place
        const unsigned rec = rec_s[r];
        const unsigned sl  = rec >> 18;
        unsigned p;
        if (rec & 0x20000u) p = atomicAdd(&a1[sl], 1u);
        else                p = atomicAdd(&a2[sl], 1u);
        if (p < CAP) ent[sl * CAP + p] = rec & 0x1FFFFu;   // plain tgt, no flag
    }
    __syncthreads();

    const int tot4 = (nn * CAP) / 4;
    u32x4* dst = (u32x4*)(ws + WS_ENTRIES + (size_t)n0 * CAP);
    const u32x4* srcp = (const u32x4*)ent;
    for (int j = threadIdx.x; j < tot4; j += 256) dst[j] = srcp[j];

    if (threadIdx.x < nn) {
        const unsigned ct = min(ctc[threadIdx.x], 0xFFFFu);       // true degree
        const unsigned p1 = min(n1c[threadIdx.x], (unsigned)CAP); // placed scale-1
        ws[WS_CNT + n0 + threadIdx.x] = ct | (p1 << 16);
    }
}

// ---------------------------------------------------------------------------
// fused gather + MFMA epilogue. 256 thr = 4 waves = 16 nodes/block.
// Direct gather from x (no Xb). Entries are class-sorted and zero-padded ->
// no ballots, no entry clamping; flag(j) = j < p1. 32-bit offsets
// (en<<8|cc<<3 or en<<7|cc<<2) keep address math to one v_lshl_add +
// SGPR-base load. fp32 path loads dwordx2 (no unpack at all).
// ---------------------------------------------------------------------------
__global__ __launch_bounds__(256) void fused_kernel(
    const unsigned* __restrict__ ws, const void* __restrict__ xv,
    void* __restrict__ outv)
{
    __shared__ __align__(16) __hip_bfloat16 sS[16][136];  // s1|s2 rows per node
    __shared__ __align__(16) __hip_bfloat16 sO[16][136];  // o1|o2 rows per node
    __shared__ int s2d[2];

    if (threadIdx.x == 0) s2d[0] = 0;
    __syncthreads();
    { unsigned u = ((const unsigned short*)xv)[threadIdx.x];
      if (((u >> 7) & 0xFF) >= 0x90) atomicOr(&s2d[0], 1); }
    __syncthreads();
    const int fp32 = s2d[0];

    const int w    = threadIdx.x >> 6;
    const int lane = threadIdx.x & 63;
    const int base = blockIdx.x * 16;

    // ---- phase A: concurrent cnt + entry loads for this wave's 4 nodes ----
    unsigned entv[4], cw[4];
#pragma unroll
    for (int i = 0; i < 4; ++i) {
        const int n = base + w * 4 + i;
        cw[i]   = ws[WS_CNT + n];
        entv[i] = ws[WS_ENTRIES + (size_t)n * CAP + (lane & 31)]; // clean: 0-padded
    }
    int degc[4], p1c[4]; unsigned degt[4];
#pragma unroll
    for (int i = 0; i < 4; ++i) {
        degt[i] = cw[i] & 0xFFFFu;
        p1c[i]  = (int)(cw[i] >> 16);
        degc[i] = (int)min(degt[i], (unsigned)CAP);
    }

    const int half = lane >> 5;       // which of the 2 rows in a chunk
    const int cc   = lane & 31;       // dim-pair index: dims 2cc, 2cc+1

    float s1x[4], s1y[4], s2x[4], s2y[4];
#pragma unroll
    for (int i = 0; i < 4; ++i) { s1x[i] = s1y[i] = s2x[i] = s2y[i] = 0.f; }

    int rmax = 0;
#pragma unroll
    for (int i = 0; i < 4; ++i) rmax = max(rmax, (degc[i] + 1) >> 1);
    rmax = (rmax + 3) & ~3;           // pad to unroll factor (pads add +0.0)

    if (fp32) {
        const char* xb = (const char*)xv;       // 256-B rows
        const unsigned ccb = (unsigned)cc << 3;
#pragma unroll 4
        for (int r = 0; r < rmax; ++r) {
#pragma unroll
            for (int i = 0; i < 4; ++i) {
                const int j = 2 * r + half;
                const unsigned en = (unsigned)__shfl((int)entv[i], j); // bpermute
                const uint2 u = *(const uint2*)(xb + (size_t)((en << 8) + ccb));
                const bool val = j < degc[i];
                const float fx = val ? __uint_as_float(u.x) : 0.f;
                const float fy = val ? __uint_as_float(u.y) : 0.f;
                const float fl = (j < p1c[i]) ? 1.f : 0.f;
                s2x[i] += fx; s2y[i] += fy;
                s1x[i] = fmaf(fl, fx, s1x[i]); s1y[i] = fmaf(fl, fy, s1y[i]);
            }
        }
    } else {
        const char* xb = (const char*)xv;       // 128-B bf16 rows
        const unsigned ccb = (unsigned)cc << 2;
#pragma unroll 4
        for (int r = 0; r < rmax; ++r) {
#pragma unroll
            for (int i = 0; i < 4; ++i) {
                const int j = 2 * r + half;
                const unsigned en = (unsigned)__shfl((int)entv[i], j); // bpermute
                unsigned u = *(const unsigned*)(xb + (size_t)((en << 7) + ccb));
                u = (j < degc[i]) ? u : 0u;
                const float fx = __uint_as_float(u << 16);          // dim 2cc
                const float fy = __uint_as_float(u & 0xFFFF0000u);  // dim 2cc+1
                const float fl = (j < p1c[i]) ? 1.f : 0.f;
                s2x[i] += fx; s2y[i] += fy;
                s1x[i] = fmaf(fl, fx, s1x[i]); s1y[i] = fmaf(fl, fy, s1y[i]);
            }
        }
    }

#pragma unroll
    for (int i = 0; i < 4; ++i) {
        const int nl = w * 4 + i;
        float a = s1x[i], b = s1y[i], c = s2x[i], d = s2y[i];
        a += __shfl_xor(a, 32); b += __shfl_xor(b, 32);
        c += __shfl_xor(c, 32); d += __shfl_xor(d, 32);
        const float inv1 = 1.0f / ((float)p1c[i] + 1e-6f);
        const float inv2 = 1.0f / ((float)degt[i] + 1e-6f);
        if (lane < 32) {   // lanes 0..31 own dim pairs 0..31
            const __hip_bfloat162 p1 = __float22bfloat162_rn({a * inv1, b * inv1});
            const __hip_bfloat162 p2 = __float22bfloat162_rn({c * inv2, d * inv2});
            *(__hip_bfloat162*)&sS[nl][2 * cc]      = p1;
            *(__hip_bfloat162*)&sS[nl][64 + 2 * cc] = p2;
        }
    }
    __syncthreads();

    // ---- phase B: MFMA epilogue; wave w computes output dims [16w,16w+16) ----
    const int m = lane & 15;          // A-row carrier / C-col index
    const int q = lane >> 4;          // quad
    const int nd = w * 16 + m;        // output dim this lane computes

    const s16x8* W1b = (const s16x8*)(ws + WS_W1B);
    const s16x8* W2b = (const s16x8*)(ws + WS_W2B);
    const s16x8* Wgb = (const s16x8*)(ws + WS_WGB);
    const float* bias = (const float*)(ws + WS_BIAS);

    const s16x8 a1c0 = *(const s16x8*)&sS[m][q * 8];
    const s16x8 a1c1 = *(const s16x8*)&sS[m][32 + q * 8];
    const s16x8 a2c0 = *(const s16x8*)&sS[m][64 + q * 8];
    const s16x8 a2c1 = *(const s16x8*)&sS[m][96 + q * 8];

    f32x4 z = {0.f, 0.f, 0.f, 0.f};
    z = __builtin_amdgcn_mfma_f32_16x16x32_bf16(a1c0, W1b[nd * 8 + q],     z, 0, 0, 0);
    z = __builtin_amdgcn_mfma_f32_16x16x32_bf16(a1c1, W1b[nd * 8 + 4 + q], z, 0, 0, 0);
    f32x4 y = {0.f, 0.f, 0.f, 0.f};
    y = __builtin_amdgcn_mfma_f32_16x16x32_bf16(a2c0, W2b[nd * 8 + q],     y, 0, 0, 0);
    y = __builtin_amdgcn_mfma_f32_16x16x32_bf16(a2c1, W2b[nd * 8 + 4 + q], y, 0, 0, 0);
    const float bb1 = bias[nd], bb2 = bias[64 + nd];
#pragma unroll
    for (int r = 0; r < 4; ++r) { z[r] += bb1; y[r] += bb2; }

#pragma unroll
    for (int r = 0; r < 4; ++r) {
        sO[q * 4 + r][nd]      = __float2bfloat16(z[r]);
        sO[q * 4 + r][64 + nd] = __float2bfloat16(y[r]);
    }
    __syncthreads();

    s16x8 ga[4];
#pragma unroll
    for (int c = 0; c < 4; ++c)
        ga[c] = *(const s16x8*)&sO[m][c * 32 + q * 8];

    f32x4 g4 = {0.f, 0.f, 0.f, 0.f};
#pragma unroll
    for (int c = 0; c < 4; ++c)
        g4 = __builtin_amdgcn_mfma_f32_16x16x32_bf16(ga[c], Wgb[nd * 16 + c * 4 + q], g4, 0, 0, 0);
    const float bbg = bias[128 + nd];

#pragma unroll
    for (int r = 0; r < 4; ++r) {
        const float g = 1.0f / (1.0f + __expf(-(g4[r] + bbg)));
        const float v = g * z[r] + (1.0f - g) * y[r];
        const size_t node = (size_t)(base + q * 4 + r);
        if (fp32) ((float*)outv)[node * 64 + nd] = v;
        else      ((__hip_bfloat16*)outv)[node * 64 + nd] = __float2bfloat16(v);
    }
}

// ---------------------------------------------------------------------------
extern "C" void kernel_launch(void* const* d_in, const int* in_sizes, int n_in,
                              void* d_out, int out_size, void* d_ws, size_t ws_size,
                              hipStream_t stream)
{
    const void* x  = d_in[0];
    const int*  ei = (const int*)d_in[1];
    unsigned* ws = (unsigned*)d_ws;

    hipMemsetAsync(ws + WS_CUR, 0, 800 * sizeof(unsigned), stream);
    prep_kernel<<<NBKT_BLKS + PREP_CONV_BLOCKS, PREP_TPB, 0, stream>>>(
        x, ei, d_in[2], d_in[3], d_in[4], d_in[5], d_in[6], d_in[7], ws);
    csr_kernel<<<NB, 256, 0, stream>>>(ws);
    fused_kernel<<<N_NODES / 16, 256, 0, stream>>>(ws, x, d_out);
}

// Round 6
// 151.353 us; speedup vs baseline: 1.0956x; 1.0956x over previous
//
#include <hip/hip_runtime.h>
#include <hip/hip_bf16.h>

#define N_NODES 100000
#define E_TOTAL 800000
#define E1      400000    // first min(4,k_max)*N edges -> scale-1 (subset of scale-2)
#define D       64
#define CAP     32        // max degree slots; P(deg>32 | Poisson(8)) ~ 2e-11/node

// ---- bucketed CSR build ----------------------------------------------------
#define NPB        256                            // nodes per bucket
#define NB         ((N_NODES + NPB - 1) / NPB)    // 391 buckets
#define BSTRIDE    (NPB * CAP)                    // 8192 u32: records alias entries span
#define BCAP       3072                           // mean 2046, sigma~45 -> 22 sigma margin
#define EPB        4096                           // edges per bucket-pass block
#define NBKT_BLKS  ((E_TOTAL + EPB - 1) / EPB)    // 196
#define PREP_TPB   512
#define EPT        (EPB / PREP_TPB)               // 8 edges/thread
#define NBP        512                            // scan width (pow2 >= NB)

typedef short s16x8 __attribute__((ext_vector_type(8)));   // 8 bf16 bit patterns
typedef float f32x4 __attribute__((ext_vector_type(4)));
typedef unsigned u32x4 __attribute__((ext_vector_type(4)));

// ws layout (u32 units):
//   cnt[N] | entries[N*CAP] | W1b[2048] | W2b[2048] | Wgb[4096] | bias[192] | cur[512] | Xb[N*32]
// cnt[n] packs: true_deg (low 16) | placed_scale1_count (high 16)
// entries: per node CAP slots, scale-1 edges first, then scale-2-only, rest ZERO.
#define WS_CNT     0
#define WS_ENTRIES (N_NODES)                        // byte 400000, 16-B aligned
#define WS_W1B     (WS_ENTRIES + N_NODES * CAP)
#define WS_W2B     (WS_W1B + 2048)
#define WS_WGB     (WS_W2B + 2048)
#define WS_BIAS    (WS_WGB + 4096)                  // b1[64] | b2[64] | bg[64] fp32
#define WS_CUR     (WS_BIAS + 192)                  // NB bucket cursors (pad to 512)
#define WS_XB      (WS_CUR + 512)                   // bf16 x copy, 16-B aligned
#define WS_NEED_BYTES ((size_t)(WS_XB + (size_t)N_NODES * D / 2) * 4)   // ~26 MB

// prep grid: bucket blocks | x-conversion blocks | weight/bias blocks
#define XCONV_BLOCKS ((N_NODES * D / 16 + PREP_TPB - 1) / PREP_TPB)   // 782
#define WCONV_BLOCKS 5

__device__ __forceinline__ float ldv(const void* p, size_t idx, int fp32)
{
    return fp32 ? ((const float*)p)[idx]
                : __bfloat162float(((const __hip_bfloat16*)p)[idx]);
}

// block-local dtype detection.
__device__ __forceinline__ void detect2(const int* ei, const unsigned short* xu,
                                        int* s2, int& e64, int& fp32)
{
    if (threadIdx.x == 0) { s2[0] = 0; s2[1] = 0; }
    __syncthreads();
    if (threadIdx.x < 16 && ei[2 * threadIdx.x + 1] != 0) atomicOr(&s2[0], 1);
    { unsigned u = xu[threadIdx.x]; if (((u >> 7) & 0xFF) >= 0x90) atomicOr(&s2[1], 1); }
    __syncthreads();
    e64 = (s2[0] == 0); fp32 = s2[1];
}

// ---------------------------------------------------------------------------
// prep: 196 bucket blocks counting-sort 4096 edges each by coarse bucket in
// LDS, then flush records in sorted flat order -> consecutive lanes write
// consecutive addresses within ~42-B per-bucket runs (write-amp ~1.5x instead
// of ~12x for 4-B scatter). 782 blocks convert x->bf16 Xb (overlaps). 5
// blocks convert weights/biases.
// ---------------------------------------------------------------------------
__global__ __launch_bounds__(512) void prep_kernel(
    const void* __restrict__ xv, const int* __restrict__ ei,
    const void* __restrict__ W1v, const void* __restrict__ b1v,
    const void* __restrict__ W2v, const void* __restrict__ b2v,
    const void* __restrict__ Wgv, const void* __restrict__ bgv,
    unsigned* __restrict__ ws, int use_xb)
{
    __shared__ int s2[2];
    __shared__ unsigned hist[NB];           // per-bucket counts (preserved)
    __shared__ unsigned sc[NBP];            // inclusive prefix scan
    __shared__ unsigned gbase[NB];          // global base per bucket
    __shared__ unsigned sorted_s[EPB];      // 16 KB: records sorted by bucket
    __shared__ unsigned short bkt_s[EPB];   // 8 KB: bucket id per sorted slot
    int e64, fp32;
    detect2(ei, (const unsigned short*)xv, s2, e64, fp32);

    const int tid = threadIdx.x;

    if (blockIdx.x < NBKT_BLKS) {                 // ---- bucket sort pass ----
        for (int j = tid; j < NB; j += PREP_TPB) hist[j] = 0;
        __syncthreads();

        const int e0 = blockIdx.x * EPB;
        int srcv[EPT], tgtv[EPT];
        if (e64) {
#pragma unroll
            for (int i = 0; i < EPT; ++i) {
                const int e  = e0 + i * PREP_TPB + tid;
                const int ec = min(e, E_TOTAL - 1);
                srcv[i] = (int)((const uint2*)ei)[ec].x;
                tgtv[i] = (int)((const uint2*)ei)[E_TOTAL + ec].x;
                if (e >= E_TOTAL) srcv[i] = -1;
            }
        } else {
#pragma unroll
            for (int i = 0; i < EPT; ++i) {
                const int e  = e0 + i * PREP_TPB + tid;
                const int ec = min(e, E_TOTAL - 1);
                srcv[i] = ei[ec];
                tgtv[i] = ei[E_TOTAL + ec];
                if (e >= E_TOTAL) srcv[i] = -1;
            }
        }

        unsigned recv[EPT], br[EPT];
#pragma unroll
        for (int i = 0; i < EPT; ++i) {           // LDS rank per bucket
            const int e = e0 + i * PREP_TPB + tid;
            br[i] = 0xFFFFFFFFu;
            if (srcv[i] >= 0) {
                const unsigned b = (unsigned)srcv[i] >> 8;   // bucket (NPB=256)
                const unsigned r = atomicAdd(&hist[b], 1u);  // rank < 4096
                recv[i] = (unsigned)tgtv[i]
                        | ((e < E1) ? 0x20000u : 0u)
                        | (((unsigned)srcv[i] & (NPB - 1)) << 18);
                br[i] = (b << 16) | r;
            }
        }
        __syncthreads();

        // inclusive prefix scan of hist into sc (NBP = PREP_TPB = 512)
        sc[tid] = (tid < NB) ? hist[tid] : 0u;
        __syncthreads();
        for (int s = 1; s < NBP; s <<= 1) {
            const unsigned v = (tid >= s) ? sc[tid - s] : 0u;
            __syncthreads();
            sc[tid] += v;
            __syncthreads();
        }

        for (int j = tid; j < NB; j += PREP_TPB) {
            const unsigned h = hist[j];
            gbase[j] = h ? atomicAdd(ws + WS_CUR + j, h) : 0u;
        }
        __syncthreads();

#pragma unroll
        for (int i = 0; i < EPT; ++i) {           // place into sorted LDS
            if (br[i] != 0xFFFFFFFFu) {
                const unsigned b = br[i] >> 16, r = br[i] & 0xFFFFu;
                const unsigned pos = (sc[b] - hist[b]) + r;
                sorted_s[pos] = recv[i];
                bkt_s[pos] = (unsigned short)b;
            }
        }
        __syncthreads();

        const unsigned tot = sc[NB - 1];          // valid edges this block
        for (unsigned k = tid; k < tot; k += PREP_TPB) {
            const unsigned b = bkt_s[k];
            const unsigned g = gbase[b] + (k - (sc[b] - hist[b]));
            if (g < BCAP)
                ws[WS_ENTRIES + (size_t)b * BSTRIDE + g] = sorted_s[k];
        }
        return;
    }

    const int bx = (int)blockIdx.x - NBKT_BLKS;
    if (bx < XCONV_BLOCKS) {                      // ---- x -> bf16 Xb ----
        if (use_xb && fp32) {
            const int gid = bx * PREP_TPB + tid;  // 16 elems/thread
            if (gid < N_NODES * D / 16) {
                __hip_bfloat16* Xb = (__hip_bfloat16*)(ws + WS_XB);
                const f32x4* src4 = (const f32x4*)xv + (size_t)gid * 4;
#pragma unroll
                for (int h = 0; h < 2; ++h) {
                    const f32x4 v0 = src4[2 * h];
                    const f32x4 v1 = src4[2 * h + 1];
                    s16x8 o;
#pragma unroll
                    for (int j = 0; j < 4; ++j) {
                        o[j]     = (short)__bfloat16_as_ushort(__float2bfloat16(v0[j]));
                        o[4 + j] = (short)__bfloat16_as_ushort(__float2bfloat16(v1[j]));
                    }
                    *(s16x8*)(Xb + (size_t)gid * 16 + h * 8) = o;
                }
            }
        }
        return;
    }

    // ---- weights / bias conversion ----
    const int gid = (bx - XCONV_BLOCKS) * PREP_TPB + tid;
    __hip_bfloat16* W1b = (__hip_bfloat16*)(ws + WS_W1B);
    __hip_bfloat16* W2b = (__hip_bfloat16*)(ws + WS_W2B);
    __hip_bfloat16* Wgb = (__hip_bfloat16*)(ws + WS_WGB);
    float* bias = (float*)(ws + WS_BIAS);

    if (gid < 2048) {                         // weights: 16384 elems, 8/thread
#pragma unroll
        for (int k = 0; k < 8; ++k) {
            const int i = gid * 8 + k;
            if (i < 4096)       W1b[i]        = __float2bfloat16(ldv(W1v, i, fp32));
            else if (i < 8192)  W2b[i - 4096] = __float2bfloat16(ldv(W2v, i - 4096, fp32));
            else                Wgb[i - 8192] = __float2bfloat16(ldv(Wgv, i - 8192, fp32));
        }
    } else if (gid < 2072) {                  // biases: 192 elems
        const int j = gid - 2048;
#pragma unroll
        for (int k = 0; k < 8; ++k) {
            const int i = j * 8 + k;
            if (i < 64)       bias[i] = ldv(b1v, i, fp32);
            else if (i < 128) bias[i] = ldv(b2v, i - 64, fp32);
            else              bias[i] = ldv(bgv, i - 128, fp32);
        }
    }
}

// ---------------------------------------------------------------------------
// csr_kernel: one block per bucket (NPB=256 nodes). Stages records in LDS,
// counts per (node, class), places scale-1 entries at [0,p1) and scale-2-only
// at [p1,deg); unused slots ZERO. Coalesced entries flush + packed cnt.
// ---------------------------------------------------------------------------
__global__ __launch_bounds__(256) void csr_kernel(unsigned* __restrict__ ws)
{
    __shared__ unsigned rec_s[BCAP];                    // 12 KB
    __shared__ __align__(16) unsigned ent[NPB * CAP];   // 32 KB
    __shared__ unsigned n1c[NPB], ctc[NPB], a1[NPB], a2[NPB];

    const int b  = blockIdx.x;
    const int n0 = b * NPB;
    const int nn = min(NPB, N_NODES - n0);

    for (int j = threadIdx.x; j < NPB; j += 256) { n1c[j] = 0; ctc[j] = 0; }
    {
        const u32x4 z = {0u, 0u, 0u, 0u};
        for (int j = threadIdx.x; j < NPB * CAP / 4; j += 256) ((u32x4*)ent)[j] = z;
    }
    const unsigned C = min(ws[WS_CUR + b], (unsigned)BCAP);
    for (unsigned r = threadIdx.x; r < C; r += 256)
        rec_s[r] = ws[WS_ENTRIES + (size_t)b * BSTRIDE + r];
    __syncthreads();

    for (unsigned r = threadIdx.x; r < C; r += 256) {   // pass 1: counts
        const unsigned rec = rec_s[r];
        const unsigned sl  = rec >> 18;
        atomicAdd(&ctc[sl], 1u);
        if (rec & 0x20000u) atomicAdd(&n1c[sl], 1u);
    }
    __syncthreads();
    for (int j = threadIdx.x; j < NPB; j += 256) {
        a1[j] = 0u;
        a2[j] = min(n1c[j], (unsigned)CAP);             // scale-2-only start
    }
    __syncthreads();
    for (unsigned r = threadIdx.x; r < C; r += 256) {   // pass 2: place
        const unsigned rec = rec_s[r];
        const unsigned sl  = rec >> 18;
        unsigned p;
        if (rec & 0x20000u) p = atomicAdd(&a1[sl], 1u);
        else                p = atomicAdd(&a2[sl], 1u);
        if (p < CAP) ent[sl * CAP + p] = rec & 0x1FFFFu;   // plain tgt, no flag
    }
    __syncthreads();

    const int tot4 = (nn * CAP) / 4;
    u32x4* dst = (u32x4*)(ws + WS_ENTRIES + (size_t)n0 * CAP);
    const u32x4* srcp = (const u32x4*)ent;
    for (int j = threadIdx.x; j < tot4; j += 256) dst[j] = srcp[j];

    if (threadIdx.x < nn) {
        const unsigned ct = min(ctc[threadIdx.x], 0xFFFFu);       // true degree
        const unsigned p1 = min(n1c[threadIdx.x], (unsigned)CAP); // placed scale-1
        ws[WS_CNT + n0 + threadIdx.x] = ct | (p1 << 16);
    }
}

// ---------------------------------------------------------------------------
// fused gather + MFMA epilogue. 256 thr = 4 waves = 16 nodes/block.
// Gather from bf16 Xb (or native bf16 x): halves random-access bytes vs fp32
// (R5 regression isolated: FETCH 94->47 MB tracks dur 63->47). Entries are
// class-sorted and zero-padded -> no ballots; flag(j) = j < p1. rmax padded
// to 2 (not 4): ~25% fewer wasted gather slots; unroll 2 = 8 loads in flight.
// ---------------------------------------------------------------------------
__global__ __launch_bounds__(256) void fused_kernel(
    const unsigned* __restrict__ ws, const void* __restrict__ xv,
    void* __restrict__ outv, int use_xb)
{
    __shared__ __align__(16) __hip_bfloat16 sS[16][136];  // s1|s2 rows per node
    __shared__ __align__(16) __hip_bfloat16 sO[16][136];  // o1|o2 rows per node
    __shared__ int s2d[2];

    if (threadIdx.x == 0) s2d[0] = 0;
    __syncthreads();
    { unsigned u = ((const unsigned short*)xv)[threadIdx.x];
      if (((u >> 7) & 0xFF) >= 0x90) atomicOr(&s2d[0], 1); }
    __syncthreads();
    const int fp32 = s2d[0];

    const int w    = threadIdx.x >> 6;
    const int lane = threadIdx.x & 63;
    const int base = blockIdx.x * 16;

    // ---- phase A: concurrent cnt + entry loads for this wave's 4 nodes ----
    unsigned entv[4], cw[4];
#pragma unroll
    for (int i = 0; i < 4; ++i) {
        const int n = base + w * 4 + i;
        cw[i]   = ws[WS_CNT + n];
        entv[i] = ws[WS_ENTRIES + (size_t)n * CAP + (lane & 31)]; // clean: 0-padded
    }
    int degc[4], p1c[4]; unsigned degt[4];
#pragma unroll
    for (int i = 0; i < 4; ++i) {
        degt[i] = cw[i] & 0xFFFFu;
        p1c[i]  = (int)(cw[i] >> 16);
        degc[i] = (int)min(degt[i], (unsigned)CAP);
    }

    const int half = lane >> 5;       // which of the 2 rows in a chunk
    const int cc   = lane & 31;       // dim-pair index: dims 2cc, 2cc+1

    float s1x[4], s1y[4], s2x[4], s2y[4];
#pragma unroll
    for (int i = 0; i < 4; ++i) { s1x[i] = s1y[i] = s2x[i] = s2y[i] = 0.f; }

    int rmax = 0;
#pragma unroll
    for (int i = 0; i < 4; ++i) rmax = max(rmax, (degc[i] + 1) >> 1);
    rmax = (rmax + 1) & ~1;           // pad to unroll factor (pads add +0.0)

    const int direct_f32 = (fp32 && !use_xb);     // fallback: no Xb space
    if (!direct_f32) {
        // bf16 gather: Xb when input fp32, else native bf16 x. 128-B rows.
        const char* xb = fp32 ? (const char*)(ws + WS_XB) : (const char*)xv;
        const unsigned ccb = (unsigned)cc << 2;
#pragma unroll 2
        for (int r = 0; r < rmax; ++r) {
#pragma unroll
            for (int i = 0; i < 4; ++i) {
                const int j = 2 * r + half;
                const unsigned en = (unsigned)__shfl((int)entv[i], j); // bpermute
                unsigned u = *(const unsigned*)(xb + (size_t)((en << 7) + ccb));
                u = (j < degc[i]) ? u : 0u;
                const float fx = __uint_as_float(u << 16);          // dim 2cc
                const float fy = __uint_as_float(u & 0xFFFF0000u);  // dim 2cc+1
                const float fl = (j < p1c[i]) ? 1.f : 0.f;
                s2x[i] += fx; s2y[i] += fy;
                s1x[i] = fmaf(fl, fx, s1x[i]); s1y[i] = fmaf(fl, fy, s1y[i]);
            }
        }
    } else {
        // direct fp32 gather fallback (only when workspace too small for Xb)
        const char* xb = (const char*)xv;       // 256-B rows
        const unsigned ccb = (unsigned)cc << 3;
#pragma unroll 2
        for (int r = 0; r < rmax; ++r) {
#pragma unroll
            for (int i = 0; i < 4; ++i) {
                const int j = 2 * r + half;
                const unsigned en = (unsigned)__shfl((int)entv[i], j); // bpermute
                const uint2 u = *(const uint2*)(xb + (size_t)((en << 8) + ccb));
                const bool val = j < degc[i];
                const float fx = val ? __uint_as_float(u.x) : 0.f;
                const float fy = val ? __uint_as_float(u.y) : 0.f;
                const float fl = (j < p1c[i]) ? 1.f : 0.f;
                s2x[i] += fx; s2y[i] += fy;
                s1x[i] = fmaf(fl, fx, s1x[i]); s1y[i] = fmaf(fl, fy, s1y[i]);
            }
        }
    }

#pragma unroll
    for (int i = 0; i < 4; ++i) {
        const int nl = w * 4 + i;
        float a = s1x[i], b = s1y[i], c = s2x[i], d = s2y[i];
        a += __shfl_xor(a, 32); b += __shfl_xor(b, 32);
        c += __shfl_xor(c, 32); d += __shfl_xor(d, 32);
        const float inv1 = 1.0f / ((float)p1c[i] + 1e-6f);
        const float inv2 = 1.0f / ((float)degt[i] + 1e-6f);
        if (lane < 32) {   // lanes 0..31 own dim pairs 0..31
            const __hip_bfloat162 p1 = __float22bfloat162_rn({a * inv1, b * inv1});
            const __hip_bfloat162 p2 = __float22bfloat162_rn({c * inv2, d * inv2});
            *(__hip_bfloat162*)&sS[nl][2 * cc]      = p1;
            *(__hip_bfloat162*)&sS[nl][64 + 2 * cc] = p2;
        }
    }
    __syncthreads();

    // ---- phase B: MFMA epilogue; wave w computes output dims [16w,16w+16) ----
    const int m = lane & 15;          // A-row carrier / C-col index
    const int q = lane >> 4;          // quad
    const int nd = w * 16 + m;        // output dim this lane computes

    const s16x8* W1b = (const s16x8*)(ws + WS_W1B);
    const s16x8* W2b = (const s16x8*)(ws + WS_W2B);
    const s16x8* Wgb = (const s16x8*)(ws + WS_WGB);
    const float* bias = (const float*)(ws + WS_BIAS);

    const s16x8 a1c0 = *(const s16x8*)&sS[m][q * 8];
    const s16x8 a1c1 = *(const s16x8*)&sS[m][32 + q * 8];
    const s16x8 a2c0 = *(const s16x8*)&sS[m][64 + q * 8];
    const s16x8 a2c1 = *(const s16x8*)&sS[m][96 + q * 8];

    f32x4 z = {0.f, 0.f, 0.f, 0.f};
    z = __builtin_amdgcn_mfma_f32_16x16x32_bf16(a1c0, W1b[nd * 8 + q],     z, 0, 0, 0);
    z = __builtin_amdgcn_mfma_f32_16x16x32_bf16(a1c1, W1b[nd * 8 + 4 + q], z, 0, 0, 0);
    f32x4 y = {0.f, 0.f, 0.f, 0.f};
    y = __builtin_amdgcn_mfma_f32_16x16x32_bf16(a2c0, W2b[nd * 8 + q],     y, 0, 0, 0);
    y = __builtin_amdgcn_mfma_f32_16x16x32_bf16(a2c1, W2b[nd * 8 + 4 + q], y, 0, 0, 0);
    const float bb1 = bias[nd], bb2 = bias[64 + nd];
#pragma unroll
    for (int r = 0; r < 4; ++r) { z[r] += bb1; y[r] += bb2; }

#pragma unroll
    for (int r = 0; r < 4; ++r) {
        sO[q * 4 + r][nd]      = __float2bfloat16(z[r]);
        sO[q * 4 + r][64 + nd] = __float2bfloat16(y[r]);
    }
    __syncthreads();

    s16x8 ga[4];
#pragma unroll
    for (int c = 0; c < 4; ++c)
        ga[c] = *(const s16x8*)&sO[m][c * 32 + q * 8];

    f32x4 g4 = {0.f, 0.f, 0.f, 0.f};
#pragma unroll
    for (int c = 0; c < 4; ++c)
        g4 = __builtin_amdgcn_mfma_f32_16x16x32_bf16(ga[c], Wgb[nd * 16 + c * 4 + q], g4, 0, 0, 0);
    const float bbg = bias[128 + nd];

#pragma unroll
    for (int r = 0; r < 4; ++r) {
        const float g = 1.0f / (1.0f + __expf(-(g4[r] + bbg)));
        const float v = g * z[r] + (1.0f - g) * y[r];
        const size_t node = (size_t)(base + q * 4 + r);
        if (fp32) ((float*)outv)[node * 64 + nd] = v;
        else      ((__hip_bfloat16*)outv)[node * 64 + nd] = __float2bfloat16(v);
    }
}

// ---------------------------------------------------------------------------
extern "C" void kernel_launch(void* const* d_in, const int* in_sizes, int n_in,
                              void* d_out, int out_size, void* d_ws, size_t ws_size,
                              hipStream_t stream)
{
    const void* x  = d_in[0];
    const int*  ei = (const int*)d_in[1];
    unsigned* ws = (unsigned*)d_ws;

    const int use_xb = (ws_size >= WS_NEED_BYTES) ? 1 : 0;   // constant per dataset

    hipMemsetAsync(ws + WS_CUR, 0, NB * sizeof(unsigned), stream);
    prep_kernel<<<NBKT_BLKS + XCONV_BLOCKS + WCONV_BLOCKS, PREP_TPB, 0, stream>>>(
        x, ei, d_in[2], d_in[3], d_in[4], d_in[5], d_in[6], d_in[7], ws, use_xb);
    csr_kernel<<<NB, 256, 0, stream>>>(ws);
    fused_kernel<<<N_NODES / 16, 256, 0, stream>>>(ws, x, d_out, use_xb);
}